// Round 1
// baseline (495.142 us; speedup 1.0000x reference)
//
#include <hip/hip_runtime.h>
#include <math.h>

#define N_TOK 2048
#define D_MODEL 512
#define NHEAD 8
#define DK 64

// XOR swizzle for 64x64 f32 LDS tiles: spreads row-groups across banks so that
// 16 lanes reading stride-64 rows see <=2-way conflicts (free).
__device__ __forceinline__ int swz(int r, int c) {
    return r * 64 + (c ^ (((r >> 2) & 7) << 2));
}

// ---------------- Stage 1: per-head projection + LayerNorm ----------------
// grid (N/16, H), block 256. Wave w handles rows n0+4w .. n0+4w+3, lane = k.
__global__ __launch_bounds__(256) void proj_ln_kernel(
    const float* __restrict__ x, const float* __restrict__ proj,
    const float* __restrict__ lnw, const float* __restrict__ lnb,
    float* __restrict__ out)
{
    __shared__ float4 xs4[16][128];  // 16 rows x 512 f32 = 32 KiB
    const int t = threadIdx.x;
    const int h = blockIdx.y;
    const int n0 = blockIdx.x * 16;

    const float4* xg = reinterpret_cast<const float4*>(x + (size_t)n0 * D_MODEL);
    for (int i = t; i < 16 * 128; i += 256) xs4[i >> 7][i & 127] = xg[i];
    __syncthreads();

    const int wave = t >> 6, lane = t & 63;
    const float* P = proj + (size_t)h * D_MODEL * DK;

    float acc[4] = {0.f, 0.f, 0.f, 0.f};
    for (int dq = 0; dq < 128; ++dq) {
        float xv[4][4];
        #pragma unroll
        for (int r = 0; r < 4; ++r) {
            float4 v = xs4[wave * 4 + r][dq];
            xv[r][0] = v.x; xv[r][1] = v.y; xv[r][2] = v.z; xv[r][3] = v.w;
        }
        #pragma unroll
        for (int u = 0; u < 4; ++u) {
            float pv = P[(dq * 4 + u) * DK + lane];
            #pragma unroll
            for (int r = 0; r < 4; ++r) acc[r] = fmaf(xv[r][u], pv, acc[r]);
        }
    }

    const float wv = lnw[lane], bv = lnb[lane];
    #pragma unroll
    for (int r = 0; r < 4; ++r) {
        float v = acc[r];
        float s = v;
        #pragma unroll
        for (int off = 32; off >= 1; off >>= 1) s += __shfl_xor(s, off);
        float mu = s * (1.0f / 64.0f);
        float d = v - mu;
        float ss = d * d;
        #pragma unroll
        for (int off = 32; off >= 1; off >>= 1) ss += __shfl_xor(ss, off);
        float var = ss * (1.0f / 64.0f);
        float rstd = rsqrtf(var + 1e-5f);
        int n = n0 + wave * 4 + r;
        out[((size_t)h * N_TOK + n) * DK + lane] = d * rstd * wv + bv;
    }
}

// ---------------- Stage 2: transpose out_w (512x512) for coalesced GEMM ----
__global__ __launch_bounds__(256) void transpose_kernel(
    const float* __restrict__ W, float* __restrict__ WT)
{
    __shared__ float tile[64][65];
    const int m0 = blockIdx.x * 64, d0 = blockIdx.y * 64;
    const int t = threadIdx.x;
    for (int i = t; i < 4096; i += 256) {
        int r = i >> 6, c = i & 63;
        tile[r][c] = W[(size_t)(m0 + r) * D_MODEL + d0 + c];
    }
    __syncthreads();
    for (int i = t; i < 4096; i += 256) {
        int r = i >> 6, c = i & 63;
        WT[(size_t)(d0 + r) * D_MODEL + m0 + c] = tile[c][r];
    }
}

// ---------------- Stage 3: RBF-modulated flash attention ----------------
// grid (N/64, H), block 256 = 4 waves. Thread (tq=t>>4, tj=t&15) owns a
// 4q x 4j score block and 4q x 4dk output block. Online softmax per q-row
// across the 16-lane tj group (shfl, same wave).
__global__ __launch_bounds__(256) void attn_kernel(
    const float* __restrict__ Q, const float* __restrict__ K,
    const float* __restrict__ V, const float* __restrict__ coords,
    const unsigned char* __restrict__ mask, float* __restrict__ att)
{
    __shared__ float Qs[64 * 64];
    __shared__ float Ks[64 * 64];
    __shared__ float Vs[64 * 64];
    __shared__ float Ps[64 * 64];   // total 64 KiB

    const int t = threadIdx.x;
    const int h = blockIdx.y;
    const int n0 = blockIdx.x * 64;
    const int tq = t >> 4, tj = t & 15;

    const float* Qh = Q + (size_t)h * N_TOK * DK;
    const float* Kh = K + (size_t)h * N_TOK * DK;
    const float* Vh = V + (size_t)h * N_TOK * DK;

    for (int i = t; i < 64 * 64; i += 256) {
        int r = i >> 6, c = i & 63;
        Qs[swz(r, c)] = Qh[(size_t)(n0 + r) * DK + c];
    }

    // head-specific gaussian spread (mirror torch.logspace semantics in f32)
    float tt = (float)h * (1.0f / 7.0f);
    float sp = 1.0f + 5.0f * (powf(20.0f, tt) - 1.0f) * (1.0f / 19.0f);
    float nis2 = -1.0f / (2.0f * sp * sp);

    float qx[4], qy[4], qz[4];
    #pragma unroll
    for (int qq = 0; qq < 4; ++qq) {
        int n = n0 + tq * 4 + qq;
        qx[qq] = coords[n * 3 + 0];
        qy[qq] = coords[n * 3 + 1];
        qz[qq] = coords[n * 3 + 2];
    }

    float m_[4], l_[4], O[4][4];
    #pragma unroll
    for (int qq = 0; qq < 4; ++qq) {
        m_[qq] = -INFINITY; l_[qq] = 0.f;
        #pragma unroll
        for (int dd = 0; dd < 4; ++dd) O[qq][dd] = 0.f;
    }

    for (int kt = 0; kt < N_TOK / 64; ++kt) {
        const int k0 = kt * 64;
        __syncthreads();   // previous tile's PV reads done
        for (int i = t; i < 64 * 64; i += 256) {
            int r = i >> 6, c = i & 63;
            Ks[swz(r, c)] = Kh[(size_t)(k0 + r) * DK + c];
            Vs[swz(r, c)] = Vh[(size_t)(k0 + r) * DK + c];
        }
        __syncthreads();

        // key coords + mask for this thread's 4 columns (L1/L2 resident)
        float kxx[4], kyy[4], kzz[4], mbit[4];
        #pragma unroll
        for (int jj = 0; jj < 4; ++jj) {
            int j = k0 + tj * 4 + jj;
            kxx[jj] = coords[j * 3 + 0];
            kyy[jj] = coords[j * 3 + 1];
            kzz[jj] = coords[j * 3 + 2];
            mbit[jj] = (float)mask[j];
        }

        // QK^T: 4x4 register block, k-outer
        float s[4][4];
        #pragma unroll
        for (int qq = 0; qq < 4; ++qq)
            #pragma unroll
            for (int jj = 0; jj < 4; ++jj) s[qq][jj] = 0.f;

        for (int k = 0; k < 64; ++k) {
            float qv[4], kv[4];
            #pragma unroll
            for (int qq = 0; qq < 4; ++qq) qv[qq] = Qs[swz(tq * 4 + qq, k)];
            #pragma unroll
            for (int jj = 0; jj < 4; ++jj) kv[jj] = Ks[swz(tj * 4 + jj, k)];
            #pragma unroll
            for (int qq = 0; qq < 4; ++qq)
                #pragma unroll
                for (int jj = 0; jj < 4; ++jj)
                    s[qq][jj] = fmaf(qv[qq], kv[jj], s[qq][jj]);
        }

        // scale, rbf, mask — reference op order: (s/8)*rbf, then where(mask,-1e9)
        #pragma unroll
        for (int qq = 0; qq < 4; ++qq) {
            #pragma unroll
            for (int jj = 0; jj < 4; ++jj) {
                float dx = qx[qq] - kxx[jj];
                float dy = qy[qq] - kyy[jj];
                float dz = qz[qq] - kzz[jj];
                float d2 = dx * dx + dy * dy + dz * dz;
                float rb = expf(d2 * nis2);
                rb = fminf(fmaxf(rb, 0.1f), 0.9f);
                float sc = s[qq][jj] * 0.125f * rb;
                s[qq][jj] = (mbit[jj] != 0.0f) ? -1e9f : sc;
            }
        }

        // online softmax per q-row (16-lane group reduce)
        #pragma unroll
        for (int qq = 0; qq < 4; ++qq) {
            float mx = fmaxf(fmaxf(s[qq][0], s[qq][1]), fmaxf(s[qq][2], s[qq][3]));
            #pragma unroll
            for (int off = 1; off < 16; off <<= 1) mx = fmaxf(mx, __shfl_xor(mx, off));
            float mn = fmaxf(m_[qq], mx);
            float corr = expf(m_[qq] - mn);
            m_[qq] = mn;
            float ps = 0.f;
            #pragma unroll
            for (int jj = 0; jj < 4; ++jj) {
                float p = expf(s[qq][jj] - mn);
                s[qq][jj] = p;
                ps += p;
            }
            #pragma unroll
            for (int off = 1; off < 16; off <<= 1) ps += __shfl_xor(ps, off);
            l_[qq] = l_[qq] * corr + ps;
            #pragma unroll
            for (int dd = 0; dd < 4; ++dd) O[qq][dd] *= corr;
            #pragma unroll
            for (int jj = 0; jj < 4; ++jj)
                Ps[swz(tq * 4 + qq, tj * 4 + jj)] = s[qq][jj];
        }

        // PV: Ps rows shared only within the 16-lane group (same wave,
        // LDS ops are in program order per wave -> no barrier needed).
        for (int j = 0; j < 64; ++j) {
            float pj[4], vj[4];
            #pragma unroll
            for (int qq = 0; qq < 4; ++qq) pj[qq] = Ps[swz(tq * 4 + qq, j)];
            #pragma unroll
            for (int dd = 0; dd < 4; ++dd) vj[dd] = Vs[swz(j, tj * 4 + dd)];
            #pragma unroll
            for (int qq = 0; qq < 4; ++qq)
                #pragma unroll
                for (int dd = 0; dd < 4; ++dd)
                    O[qq][dd] = fmaf(pj[qq], vj[dd], O[qq][dd]);
        }
    }

    // normalize + write in transposed layout att[n][k*H + h]
    #pragma unroll
    for (int qq = 0; qq < 4; ++qq) {
        float inv = 1.0f / l_[qq];
        int n = n0 + tq * 4 + qq;
        #pragma unroll
        for (int dd = 0; dd < 4; ++dd) {
            int kcol = tj * 4 + dd;
            att[(size_t)n * D_MODEL + kcol * NHEAD + h] = O[qq][dd] * inv;
        }
    }
}

// ---------------- Stage 4: output projection ----------------
// grid (N/8), block 256; thread t computes cols {t, t+256} for 8 rows.
__global__ __launch_bounds__(256) void out_proj_kernel(
    const float* __restrict__ att, const float* __restrict__ WT,
    const float* __restrict__ bias, float* __restrict__ out)
{
    __shared__ float4 as4[8][128];  // 16 KiB
    const int t = threadIdx.x;
    const int n0 = blockIdx.x * 8;

    const float4* ag = reinterpret_cast<const float4*>(att + (size_t)n0 * D_MODEL);
    for (int i = t; i < 8 * 128; i += 256) as4[i >> 7][i & 127] = ag[i];
    __syncthreads();

    float acc[8][2];
    #pragma unroll
    for (int r = 0; r < 8; ++r) { acc[r][0] = 0.f; acc[r][1] = 0.f; }

    for (int dq = 0; dq < 128; ++dq) {
        float a[8][4];
        #pragma unroll
        for (int r = 0; r < 8; ++r) {
            float4 v = as4[r][dq];
            a[r][0] = v.x; a[r][1] = v.y; a[r][2] = v.z; a[r][3] = v.w;
        }
        #pragma unroll
        for (int u = 0; u < 4; ++u) {
            int d = dq * 4 + u;
            float w0 = WT[(size_t)d * D_MODEL + t];
            float w1 = WT[(size_t)d * D_MODEL + 256 + t];
            #pragma unroll
            for (int r = 0; r < 8; ++r) {
                acc[r][0] = fmaf(a[r][u], w0, acc[r][0]);
                acc[r][1] = fmaf(a[r][u], w1, acc[r][1]);
            }
        }
    }

    const float b0 = bias[t], b1 = bias[256 + t];
    #pragma unroll
    for (int r = 0; r < 8; ++r) {
        out[(size_t)(n0 + r) * D_MODEL + t] = acc[r][0] + b0;
        out[(size_t)(n0 + r) * D_MODEL + 256 + t] = acc[r][1] + b1;
    }
}

extern "C" void kernel_launch(void* const* d_in, const int* in_sizes, int n_in,
                              void* d_out, int out_size, void* d_ws, size_t ws_size,
                              hipStream_t stream)
{
    const float* q      = (const float*)d_in[0];
    const float* k      = (const float*)d_in[1];
    const float* v      = (const float*)d_in[2];
    const float* coords = (const float*)d_in[3];
    const unsigned char* mask = (const unsigned char*)d_in[4];
    const float* q_proj = (const float*)d_in[5];
    const float* k_proj = (const float*)d_in[6];
    const float* v_proj = (const float*)d_in[7];
    const float* q_ln_w = (const float*)d_in[8];
    const float* q_ln_b = (const float*)d_in[9];
    const float* k_ln_w = (const float*)d_in[10];
    const float* k_ln_b = (const float*)d_in[11];
    const float* v_ln_w = (const float*)d_in[12];
    const float* v_ln_b = (const float*)d_in[13];
    const float* out_w  = (const float*)d_in[14];
    const float* out_b  = (const float*)d_in[15];
    float* out = (float*)d_out;

    float* ws  = (float*)d_ws;
    float* Qo  = ws;                 // H*N*DK = 1048576 floats
    float* Ko  = ws + 1048576;
    float* Vo  = ws + 2097152;
    float* ATT = ws + 3145728;       // N*D_MODEL
    float* WT  = ws + 4194304;       // D_MODEL*D_MODEL

    dim3 blk(256);
    proj_ln_kernel<<<dim3(N_TOK / 16, NHEAD), blk, 0, stream>>>(q, q_proj, q_ln_w, q_ln_b, Qo);
    proj_ln_kernel<<<dim3(N_TOK / 16, NHEAD), blk, 0, stream>>>(k, k_proj, k_ln_w, k_ln_b, Ko);
    proj_ln_kernel<<<dim3(N_TOK / 16, NHEAD), blk, 0, stream>>>(v, v_proj, v_ln_w, v_ln_b, Vo);
    transpose_kernel<<<dim3(8, 8), blk, 0, stream>>>(out_w, WT);
    attn_kernel<<<dim3(N_TOK / 64, NHEAD), blk, 0, stream>>>(Qo, Ko, Vo, coords, mask, ATT);
    out_proj_kernel<<<dim3(N_TOK / 8), blk, 0, stream>>>(ATT, WT, out_b, out);
}

// Round 2
// 494.237 us; speedup vs baseline: 1.0018x; 1.0018x over previous
//
#include <hip/hip_runtime.h>
#include <math.h>

#define N_TOK 2048
#define D_MODEL 512
#define NHEAD 8
#define DK 64

// XOR swizzle for 64x64 f32 LDS tiles: spreads row-groups across banks so that
// 16 lanes reading stride-64 rows see <=2-way conflicts (free).
__device__ __forceinline__ int swz(int r, int c) {
    return r * 64 + (c ^ (((r >> 2) & 7) << 2));
}

// ---------------- Stage 1: per-head projection + LayerNorm ----------------
// grid (N/16, H), block 256. Wave w handles rows n0+4w .. n0+4w+3, lane = k.
__global__ __launch_bounds__(256) void proj_ln_kernel(
    const float* __restrict__ x, const float* __restrict__ proj,
    const float* __restrict__ lnw, const float* __restrict__ lnb,
    float* __restrict__ out)
{
    __shared__ float4 xs4[16][128];  // 16 rows x 512 f32 = 32 KiB
    const int t = threadIdx.x;
    const int h = blockIdx.y;
    const int n0 = blockIdx.x * 16;

    const float4* xg = reinterpret_cast<const float4*>(x + (size_t)n0 * D_MODEL);
    for (int i = t; i < 16 * 128; i += 256) xs4[i >> 7][i & 127] = xg[i];
    __syncthreads();

    const int wave = t >> 6, lane = t & 63;
    const float* P = proj + (size_t)h * D_MODEL * DK;

    float acc[4] = {0.f, 0.f, 0.f, 0.f};
    for (int dq = 0; dq < 128; ++dq) {
        float xv[4][4];
        #pragma unroll
        for (int r = 0; r < 4; ++r) {
            float4 v = xs4[wave * 4 + r][dq];
            xv[r][0] = v.x; xv[r][1] = v.y; xv[r][2] = v.z; xv[r][3] = v.w;
        }
        #pragma unroll
        for (int u = 0; u < 4; ++u) {
            float pv = P[(dq * 4 + u) * DK + lane];
            #pragma unroll
            for (int r = 0; r < 4; ++r) acc[r] = fmaf(xv[r][u], pv, acc[r]);
        }
    }

    const float wv = lnw[lane], bv = lnb[lane];
    #pragma unroll
    for (int r = 0; r < 4; ++r) {
        float v = acc[r];
        float s = v;
        #pragma unroll
        for (int off = 32; off >= 1; off >>= 1) s += __shfl_xor(s, off);
        float mu = s * (1.0f / 64.0f);
        float d = v - mu;
        float ss = d * d;
        #pragma unroll
        for (int off = 32; off >= 1; off >>= 1) ss += __shfl_xor(ss, off);
        float var = ss * (1.0f / 64.0f);
        float rstd = rsqrtf(var + 1e-5f);
        int n = n0 + wave * 4 + r;
        out[((size_t)h * N_TOK + n) * DK + lane] = d * rstd * wv + bv;
    }
}

// ---------------- Stage 2: transpose out_w (512x512) for coalesced GEMM ----
__global__ __launch_bounds__(256) void transpose_kernel(
    const float* __restrict__ W, float* __restrict__ WT)
{
    __shared__ float tile[64][65];
    const int m0 = blockIdx.x * 64, d0 = blockIdx.y * 64;
    const int t = threadIdx.x;
    for (int i = t; i < 4096; i += 256) {
        int r = i >> 6, c = i & 63;
        tile[r][c] = W[(size_t)(m0 + r) * D_MODEL + d0 + c];
    }
    __syncthreads();
    for (int i = t; i < 4096; i += 256) {
        int r = i >> 6, c = i & 63;
        WT[(size_t)(d0 + r) * D_MODEL + m0 + c] = tile[c][r];
    }
}

// ---------------- Stage 3: RBF-modulated flash attention ----------------
// grid (N/64, H), block 256 = 4 waves. Thread (tq=t>>4, tj=t&15) owns a
// 4q x 4j score block and 4q x 4dk output block. Online softmax per q-row
// across the 16-lane tj group (shfl, same wave).
__global__ __launch_bounds__(256) void attn_kernel(
    const float* __restrict__ Q, const float* __restrict__ K,
    const float* __restrict__ V, const float* __restrict__ coords,
    const unsigned char* __restrict__ mask, float* __restrict__ att)
{
    __shared__ float Qs[64 * 64];
    __shared__ float Ks[64 * 64];
    __shared__ float Vs[64 * 64];
    __shared__ float Ps[64 * 64];   // total 64 KiB

    const int t = threadIdx.x;
    const int h = blockIdx.y;
    const int n0 = blockIdx.x * 64;
    const int tq = t >> 4, tj = t & 15;

    const float* Qh = Q + (size_t)h * N_TOK * DK;
    const float* Kh = K + (size_t)h * N_TOK * DK;
    const float* Vh = V + (size_t)h * N_TOK * DK;

    for (int i = t; i < 64 * 64; i += 256) {
        int r = i >> 6, c = i & 63;
        Qs[swz(r, c)] = Qh[(size_t)(n0 + r) * DK + c];
    }

    // head-specific gaussian spread (mirror torch.logspace semantics in f32)
    float tt = (float)h * (1.0f / 7.0f);
    float sp = 1.0f + 5.0f * (powf(20.0f, tt) - 1.0f) * (1.0f / 19.0f);
    float nis2 = -1.0f / (2.0f * sp * sp);

    float qx[4], qy[4], qz[4];
    #pragma unroll
    for (int qq = 0; qq < 4; ++qq) {
        int n = n0 + tq * 4 + qq;
        qx[qq] = coords[n * 3 + 0];
        qy[qq] = coords[n * 3 + 1];
        qz[qq] = coords[n * 3 + 2];
    }

    float m_[4], l_[4], O[4][4];
    #pragma unroll
    for (int qq = 0; qq < 4; ++qq) {
        m_[qq] = -INFINITY; l_[qq] = 0.f;
        #pragma unroll
        for (int dd = 0; dd < 4; ++dd) O[qq][dd] = 0.f;
    }

    for (int kt = 0; kt < N_TOK / 64; ++kt) {
        const int k0 = kt * 64;
        __syncthreads();   // previous tile's PV reads done
        for (int i = t; i < 64 * 64; i += 256) {
            int r = i >> 6, c = i & 63;
            Ks[swz(r, c)] = Kh[(size_t)(k0 + r) * DK + c];
            Vs[swz(r, c)] = Vh[(size_t)(k0 + r) * DK + c];
        }
        __syncthreads();

        // key coords + mask for this thread's 4 columns (L1/L2 resident)
        float kxx[4], kyy[4], kzz[4], mbit[4];
        #pragma unroll
        for (int jj = 0; jj < 4; ++jj) {
            int j = k0 + tj * 4 + jj;
            kxx[jj] = coords[j * 3 + 0];
            kyy[jj] = coords[j * 3 + 1];
            kzz[jj] = coords[j * 3 + 2];
            mbit[jj] = (float)mask[j];
        }

        // QK^T: 4x4 register block, k-outer
        float s[4][4];
        #pragma unroll
        for (int qq = 0; qq < 4; ++qq)
            #pragma unroll
            for (int jj = 0; jj < 4; ++jj) s[qq][jj] = 0.f;

        for (int k = 0; k < 64; ++k) {
            float qv[4], kv[4];
            #pragma unroll
            for (int qq = 0; qq < 4; ++qq) qv[qq] = Qs[swz(tq * 4 + qq, k)];
            #pragma unroll
            for (int jj = 0; jj < 4; ++jj) kv[jj] = Ks[swz(tj * 4 + jj, k)];
            #pragma unroll
            for (int qq = 0; qq < 4; ++qq)
                #pragma unroll
                for (int jj = 0; jj < 4; ++jj)
                    s[qq][jj] = fmaf(qv[qq], kv[jj], s[qq][jj]);
        }

        // scale, rbf, mask — reference op order: (s/8)*rbf, then where(mask,-1e9)
        #pragma unroll
        for (int qq = 0; qq < 4; ++qq) {
            #pragma unroll
            for (int jj = 0; jj < 4; ++jj) {
                float dx = qx[qq] - kxx[jj];
                float dy = qy[qq] - kyy[jj];
                float dz = qz[qq] - kzz[jj];
                float d2 = dx * dx + dy * dy + dz * dz;
                float rb = expf(d2 * nis2);
                rb = fminf(fmaxf(rb, 0.1f), 0.9f);
                float sc = s[qq][jj] * 0.125f * rb;
                s[qq][jj] = (mbit[jj] != 0.0f) ? -1e9f : sc;
            }
        }

        // online softmax per q-row (16-lane group reduce)
        #pragma unroll
        for (int qq = 0; qq < 4; ++qq) {
            float mx = fmaxf(fmaxf(s[qq][0], s[qq][1]), fmaxf(s[qq][2], s[qq][3]));
            #pragma unroll
            for (int off = 1; off < 16; off <<= 1) mx = fmaxf(mx, __shfl_xor(mx, off));
            float mn = fmaxf(m_[qq], mx);
            float corr = expf(m_[qq] - mn);
            m_[qq] = mn;
            float ps = 0.f;
            #pragma unroll
            for (int jj = 0; jj < 4; ++jj) {
                float p = expf(s[qq][jj] - mn);
                s[qq][jj] = p;
                ps += p;
            }
            #pragma unroll
            for (int off = 1; off < 16; off <<= 1) ps += __shfl_xor(ps, off);
            l_[qq] = l_[qq] * corr + ps;
            #pragma unroll
            for (int dd = 0; dd < 4; ++dd) O[qq][dd] *= corr;
            #pragma unroll
            for (int jj = 0; jj < 4; ++jj)
                Ps[swz(tq * 4 + qq, tj * 4 + jj)] = s[qq][jj];
        }

        // PV: Ps rows shared only within the 16-lane group (same wave,
        // LDS ops are in program order per wave -> no barrier needed).
        for (int j = 0; j < 64; ++j) {
            float pj[4], vj[4];
            #pragma unroll
            for (int qq = 0; qq < 4; ++qq) pj[qq] = Ps[swz(tq * 4 + qq, j)];
            #pragma unroll
            for (int dd = 0; dd < 4; ++dd) vj[dd] = Vs[swz(j, tj * 4 + dd)];
            #pragma unroll
            for (int qq = 0; qq < 4; ++qq)
                #pragma unroll
                for (int dd = 0; dd < 4; ++dd)
                    O[qq][dd] = fmaf(pj[qq], vj[dd], O[qq][dd]);
        }
    }

    // normalize + write in transposed layout att[n][k*H + h]
    #pragma unroll
    for (int qq = 0; qq < 4; ++qq) {
        float inv = 1.0f / l_[qq];
        int n = n0 + tq * 4 + qq;
        #pragma unroll
        for (int dd = 0; dd < 4; ++dd) {
            int kcol = tj * 4 + dd;
            att[(size_t)n * D_MODEL + kcol * NHEAD + h] = O[qq][dd] * inv;
        }
    }
}

// ---------------- Stage 4: output projection ----------------
// grid (N/8), block 256; thread t computes cols {t, t+256} for 8 rows.
__global__ __launch_bounds__(256) void out_proj_kernel(
    const float* __restrict__ att, const float* __restrict__ WT,
    const float* __restrict__ bias, float* __restrict__ out)
{
    __shared__ float4 as4[8][128];  // 16 KiB
    const int t = threadIdx.x;
    const int n0 = blockIdx.x * 8;

    const float4* ag = reinterpret_cast<const float4*>(att + (size_t)n0 * D_MODEL);
    for (int i = t; i < 8 * 128; i += 256) as4[i >> 7][i & 127] = ag[i];
    __syncthreads();

    float acc[8][2];
    #pragma unroll
    for (int r = 0; r < 8; ++r) { acc[r][0] = 0.f; acc[r][1] = 0.f; }

    for (int dq = 0; dq < 128; ++dq) {
        float a[8][4];
        #pragma unroll
        for (int r = 0; r < 8; ++r) {
            float4 v = as4[r][dq];
            a[r][0] = v.x; a[r][1] = v.y; a[r][2] = v.z; a[r][3] = v.w;
        }
        #pragma unroll
        for (int u = 0; u < 4; ++u) {
            int d = dq * 4 + u;
            float w0 = WT[(size_t)d * D_MODEL + t];
            float w1 = WT[(size_t)d * D_MODEL + 256 + t];
            #pragma unroll
            for (int r = 0; r < 8; ++r) {
                acc[r][0] = fmaf(a[r][u], w0, acc[r][0]);
                acc[r][1] = fmaf(a[r][u], w1, acc[r][1]);
            }
        }
    }

    const float b0 = bias[t], b1 = bias[256 + t];
    #pragma unroll
    for (int r = 0; r < 8; ++r) {
        out[(size_t)(n0 + r) * D_MODEL + t] = acc[r][0] + b0;
        out[(size_t)(n0 + r) * D_MODEL + 256 + t] = acc[r][1] + b1;
    }
}

extern "C" void kernel_launch(void* const* d_in, const int* in_sizes, int n_in,
                              void* d_out, int out_size, void* d_ws, size_t ws_size,
                              hipStream_t stream)
{
    const float* q      = (const float*)d_in[0];
    const float* k      = (const float*)d_in[1];
    const float* v      = (const float*)d_in[2];
    const float* coords = (const float*)d_in[3];
    const unsigned char* mask = (const unsigned char*)d_in[4];
    const float* q_proj = (const float*)d_in[5];
    const float* k_proj = (const float*)d_in[6];
    const float* v_proj = (const float*)d_in[7];
    const float* q_ln_w = (const float*)d_in[8];
    const float* q_ln_b = (const float*)d_in[9];
    const float* k_ln_w = (const float*)d_in[10];
    const float* k_ln_b = (const float*)d_in[11];
    const float* v_ln_w = (const float*)d_in[12];
    const float* v_ln_b = (const float*)d_in[13];
    const float* out_w  = (const float*)d_in[14];
    const float* out_b  = (const float*)d_in[15];
    float* out = (float*)d_out;

    float* ws  = (float*)d_ws;
    float* Qo  = ws;                 // H*N*DK = 1048576 floats
    float* Ko  = ws + 1048576;
    float* Vo  = ws + 2097152;
    float* ATT = ws + 3145728;       // N*D_MODEL
    float* WT  = ws + 4194304;       // D_MODEL*D_MODEL

    dim3 blk(256);
    proj_ln_kernel<<<dim3(N_TOK / 16, NHEAD), blk, 0, stream>>>(q, q_proj, q_ln_w, q_ln_b, Qo);
    proj_ln_kernel<<<dim3(N_TOK / 16, NHEAD), blk, 0, stream>>>(k, k_proj, k_ln_w, k_ln_b, Ko);
    proj_ln_kernel<<<dim3(N_TOK / 16, NHEAD), blk, 0, stream>>>(v, v_proj, v_ln_w, v_ln_b, Vo);
    transpose_kernel<<<dim3(8, 8), blk, 0, stream>>>(out_w, WT);
    attn_kernel<<<dim3(N_TOK / 64, NHEAD), blk, 0, stream>>>(Qo, Ko, Vo, coords, mask, ATT);
    out_proj_kernel<<<dim3(N_TOK / 8), blk, 0, stream>>>(ATT, WT, out_b, out);
}

// Round 3
// 239.511 us; speedup vs baseline: 2.0673x; 2.0635x over previous
//
#include <hip/hip_runtime.h>
#include <math.h>

#define N_TOK 2048
#define D_MODEL 512
#define NHEAD 8
#define DK 64

typedef __attribute__((ext_vector_type(8))) short short8;
typedef __attribute__((ext_vector_type(4))) short short4v;
typedef __attribute__((ext_vector_type(4))) float f32x4;

__device__ __forceinline__ short f2bf(float x) {
    unsigned u = __float_as_uint(x);
    u = (u + 0x7fffu + ((u >> 16) & 1u)) >> 16;   // round-to-nearest-even
    return (short)u;
}

// ---------------- Stage 1: per-head projection + LayerNorm -> bf16 ----------
// grid (N/16, H), block 256. Wave w handles rows n0+4w..n0+4w+3, lane = dk.
// TRANSPOSE=0: out[h][n][dk] bf16.  TRANSPOSE=1 (V): out[h][dk][n] bf16.
template <int TRANSPOSE>
__global__ __launch_bounds__(256) void proj_ln_kernel(
    const float* __restrict__ x, const float* __restrict__ proj,
    const float* __restrict__ lnw, const float* __restrict__ lnb,
    short* __restrict__ out)
{
    __shared__ float4 xs4[16][128];  // 16 rows x 512 f32 = 32 KiB
    __shared__ float tls[16][65];    // transpose staging (TRANSPOSE=1)
    const int t = threadIdx.x;
    const int h = blockIdx.y;
    const int n0 = blockIdx.x * 16;

    const float4* xg = reinterpret_cast<const float4*>(x + (size_t)n0 * D_MODEL);
    for (int i = t; i < 16 * 128; i += 256) xs4[i >> 7][i & 127] = xg[i];
    __syncthreads();

    const int wave = t >> 6, lane = t & 63;
    const float* P = proj + (size_t)h * D_MODEL * DK;

    float acc[4] = {0.f, 0.f, 0.f, 0.f};
    for (int dq = 0; dq < 128; ++dq) {
        float xv[4][4];
        #pragma unroll
        for (int r = 0; r < 4; ++r) {
            float4 v = xs4[wave * 4 + r][dq];
            xv[r][0] = v.x; xv[r][1] = v.y; xv[r][2] = v.z; xv[r][3] = v.w;
        }
        #pragma unroll
        for (int u = 0; u < 4; ++u) {
            float pv = P[(dq * 4 + u) * DK + lane];
            #pragma unroll
            for (int r = 0; r < 4; ++r) acc[r] = fmaf(xv[r][u], pv, acc[r]);
        }
    }

    const float wv = lnw[lane], bv = lnb[lane];
    #pragma unroll
    for (int r = 0; r < 4; ++r) {
        float v = acc[r];
        float s = v;
        #pragma unroll
        for (int off = 32; off >= 1; off >>= 1) s += __shfl_xor(s, off);
        float mu = s * (1.0f / 64.0f);
        float d = v - mu;
        float ss = d * d;
        #pragma unroll
        for (int off = 32; off >= 1; off >>= 1) ss += __shfl_xor(ss, off);
        float var = ss * (1.0f / 64.0f);
        float rstd = rsqrtf(var + 1e-5f);
        float val = d * rstd * wv + bv;
        if (TRANSPOSE == 0) {
            out[((size_t)h * N_TOK + n0 + wave * 4 + r) * DK + lane] = f2bf(val);
        } else {
            tls[wave * 4 + r][lane] = val;
        }
    }
    if (TRANSPOSE) {
        __syncthreads();
        const int dk = t >> 2, ng = t & 3;
        short4v pk;
        #pragma unroll
        for (int i = 0; i < 4; ++i) pk[i] = f2bf(tls[ng * 4 + i][dk]);
        *(short4v*)(out + ((size_t)h * DK + dk) * N_TOK + n0 + ng * 4) = pk;
    }
}

// ---------------- Stage 2: transpose out_w (512x512) for coalesced GEMM ----
__global__ __launch_bounds__(256) void transpose_kernel(
    const float* __restrict__ W, float* __restrict__ WT)
{
    __shared__ float tile[64][65];
    const int m0 = blockIdx.x * 64, d0 = blockIdx.y * 64;
    const int t = threadIdx.x;
    for (int i = t; i < 4096; i += 256) {
        int r = i >> 6, c = i & 63;
        tile[r][c] = W[(size_t)(m0 + r) * D_MODEL + d0 + c];
    }
    __syncthreads();
    for (int i = t; i < 4096; i += 256) {
        int r = i >> 6, c = i & 63;
        WT[(size_t)(d0 + r) * D_MODEL + m0 + c] = tile[c][r];
    }
}

// ---------------- Stage 3: RBF-modulated flash attention (bf16 MFMA) -------
// grid (N/32, H), block 128 = 2 waves; wave w owns q-rows n0+16w..+15.
// mfma_f32_16x16x32_bf16, m97-pattern: [row][64] LDS tiles, contiguous b128
// frag reads, XOR swizzle elem ^= (row&7)<<3 (16B granular) for bank spread.
__global__ __launch_bounds__(128) void attn_kernel(
    const short* __restrict__ Qbf, const short* __restrict__ Kbf,
    const short* __restrict__ Vtbf, const float* __restrict__ coords,
    const unsigned char* __restrict__ mask, float* __restrict__ att)
{
    __shared__ short Ks[64 * 64];    // [k][dk]   8 KiB
    __shared__ short Vts[64 * 64];   // [d][k]    8 KiB
    __shared__ short Pls[2][16 * 64];// per-wave P [q][k]  4 KiB

    const int tid = threadIdx.x;
    const int w = tid >> 6, l = tid & 63;
    const int l15 = l & 15, lg = l >> 4;
    const int h = blockIdx.y;
    const int n0 = blockIdx.x * 32;

    // Q A-fragments straight from global (rows w*16+l15, k-slice lg*8..+7)
    const short* Qrow = Qbf + ((size_t)h * N_TOK + n0 + w * 16 + l15) * DK + lg * 8;
    const short8 qf0 = *(const short8*)(Qrow);
    const short8 qf1 = *(const short8*)(Qrow + 32);

    // head-specific gaussian spread (torch.logspace semantics)
    float tt = (float)h * (1.0f / 7.0f);
    float sp = 1.0f + 5.0f * (powf(20.0f, tt) - 1.0f) * (1.0f / 19.0f);
    float nis2 = -1.0f / (2.0f * sp * sp);

    // q coords for C-rows q = n0 + w*16 + lg*4 + reg
    float qx[4], qy[4], qz[4];
    #pragma unroll
    for (int reg = 0; reg < 4; ++reg) {
        int n = n0 + w * 16 + lg * 4 + reg;
        qx[reg] = coords[n * 3 + 0];
        qy[reg] = coords[n * 3 + 1];
        qz[reg] = coords[n * 3 + 2];
    }

    const f32x4 zero4 = {0.f, 0.f, 0.f, 0.f};
    float m_[4], l_[4];
    f32x4 oacc[4];
    #pragma unroll
    for (int i = 0; i < 4; ++i) { m_[i] = -INFINITY; l_[i] = 0.f; oacc[i] = zero4; }

    short* Pw = &Pls[w][0];

    for (int kt = 0; kt < N_TOK / 64; ++kt) {
        const int k0 = kt * 64;
        __syncthreads();   // prior tile's reads complete
        // stage K tile [k][dk] and V^T tile [d][k], swizzled, 16B chunks
        #pragma unroll
        for (int i = 0; i < 4; ++i) {
            int c = tid + i * 128;
            int r = c >> 3, g = c & 7;
            short8 kv = *(const short8*)(Kbf + ((size_t)h * N_TOK + k0 + r) * DK + g * 8);
            *(short8*)(Ks + r * 64 + ((g * 8) ^ ((r & 7) << 3))) = kv;
            short8 vv = *(const short8*)(Vtbf + ((size_t)h * DK + r) * N_TOK + k0 + g * 8);
            *(short8*)(Vts + r * 64 + ((g * 8) ^ ((r & 7) << 3))) = vv;
        }
        __syncthreads();

        // QK^T: S[16q x 64k] = 4 n-chunks x 2 k-steps
        f32x4 sacc[4];
        #pragma unroll
        for (int nc = 0; nc < 4; ++nc) sacc[nc] = zero4;
        #pragma unroll
        for (int nc = 0; nc < 4; ++nc) {
            int krow = nc * 16 + l15;
            int eb = krow * 64, sw = (krow & 7) << 3;
            short8 kb0 = *(const short8*)(Ks + eb + ((lg * 8) ^ sw));
            sacc[nc] = __builtin_amdgcn_mfma_f32_16x16x32_bf16(qf0, kb0, sacc[nc], 0, 0, 0);
            short8 kb1 = *(const short8*)(Ks + eb + ((32 + lg * 8) ^ sw));
            sacc[nc] = __builtin_amdgcn_mfma_f32_16x16x32_bf16(qf1, kb1, sacc[nc], 0, 0, 0);
        }

        // key coords + mask for this lane's 4 k-columns (L1-resident)
        float kx[4], ky[4], kz[4], km[4];
        #pragma unroll
        for (int nc = 0; nc < 4; ++nc) {
            int j = k0 + nc * 16 + l15;
            kx[nc] = coords[j * 3 + 0];
            ky[nc] = coords[j * 3 + 1];
            kz[nc] = coords[j * 3 + 2];
            km[nc] = (float)mask[j];
        }

        // rbf + mask + online softmax per q-row (reduce over 16-lane group)
        float corr[4];
        #pragma unroll
        for (int reg = 0; reg < 4; ++reg) {
            float sv[4];
            #pragma unroll
            for (int nc = 0; nc < 4; ++nc) {
                float dx = qx[reg] - kx[nc];
                float dy = qy[reg] - ky[nc];
                float dz = qz[reg] - kz[nc];
                float d2 = dx * dx + dy * dy + dz * dz;
                float rb = __expf(d2 * nis2);
                rb = fminf(fmaxf(rb, 0.1f), 0.9f);
                float sc = sacc[nc][reg] * 0.125f * rb;
                sv[nc] = (km[nc] != 0.0f) ? -1e9f : sc;
            }
            float mx = fmaxf(fmaxf(sv[0], sv[1]), fmaxf(sv[2], sv[3]));
            #pragma unroll
            for (int off = 1; off < 16; off <<= 1) mx = fmaxf(mx, __shfl_xor(mx, off));
            float mn = fmaxf(m_[reg], mx);
            float c0 = __expf(m_[reg] - mn);
            m_[reg] = mn;
            float p[4], ps = 0.f;
            #pragma unroll
            for (int nc = 0; nc < 4; ++nc) { p[nc] = __expf(sv[nc] - mn); ps += p[nc]; }
            #pragma unroll
            for (int off = 1; off < 16; off <<= 1) ps += __shfl_xor(ps, off);
            l_[reg] = l_[reg] * c0 + ps;
            corr[reg] = c0;
            // P -> LDS (bf16), row = lg*4+reg, col = nc*16+l15, swizzled
            int prow = lg * 4 + reg;
            int pb = prow * 64, psw = (prow & 7) << 3;
            #pragma unroll
            for (int nc = 0; nc < 4; ++nc)
                Pw[pb + ((nc * 16 + l15) ^ psw)] = f2bf(p[nc]);
        }
        #pragma unroll
        for (int dc = 0; dc < 4; ++dc)
            #pragma unroll
            for (int reg = 0; reg < 4; ++reg) oacc[dc][reg] *= corr[reg];

        // PV: A = P (from own wave's LDS, program-order safe), B = V^T rows
        short8 pa0, pa1;
        {
            int pb = l15 * 64, sw2 = (l15 & 7) << 3;
            pa0 = *(const short8*)(Pw + pb + ((lg * 8) ^ sw2));
            pa1 = *(const short8*)(Pw + pb + ((32 + lg * 8) ^ sw2));
        }
        #pragma unroll
        for (int dc = 0; dc < 4; ++dc) {
            int dr = dc * 16 + l15;
            int eb = dr * 64, sw3 = (dr & 7) << 3;
            short8 vb0 = *(const short8*)(Vts + eb + ((lg * 8) ^ sw3));
            oacc[dc] = __builtin_amdgcn_mfma_f32_16x16x32_bf16(pa0, vb0, oacc[dc], 0, 0, 0);
            short8 vb1 = *(const short8*)(Vts + eb + ((32 + lg * 8) ^ sw3));
            oacc[dc] = __builtin_amdgcn_mfma_f32_16x16x32_bf16(pa1, vb1, oacc[dc], 0, 0, 0);
        }
    }

    // normalize + write transposed layout att[n][d*H + h]
    float rl[4];
    #pragma unroll
    for (int reg = 0; reg < 4; ++reg) rl[reg] = 1.0f / l_[reg];
    #pragma unroll
    for (int dc = 0; dc < 4; ++dc) {
        int d = dc * 16 + l15;
        #pragma unroll
        for (int reg = 0; reg < 4; ++reg) {
            int n = n0 + w * 16 + lg * 4 + reg;
            att[(size_t)n * D_MODEL + d * NHEAD + h] = oacc[dc][reg] * rl[reg];
        }
    }
}

// ---------------- Stage 4: output projection ----------------
__global__ __launch_bounds__(256) void out_proj_kernel(
    const float* __restrict__ att, const float* __restrict__ WT,
    const float* __restrict__ bias, float* __restrict__ out)
{
    __shared__ float4 as4[8][128];  // 16 KiB
    const int t = threadIdx.x;
    const int n0 = blockIdx.x * 8;

    const float4* ag = reinterpret_cast<const float4*>(att + (size_t)n0 * D_MODEL);
    for (int i = t; i < 8 * 128; i += 256) as4[i >> 7][i & 127] = ag[i];
    __syncthreads();

    float acc[8][2];
    #pragma unroll
    for (int r = 0; r < 8; ++r) { acc[r][0] = 0.f; acc[r][1] = 0.f; }

    for (int dq = 0; dq < 128; ++dq) {
        float a[8][4];
        #pragma unroll
        for (int r = 0; r < 8; ++r) {
            float4 v = as4[r][dq];
            a[r][0] = v.x; a[r][1] = v.y; a[r][2] = v.z; a[r][3] = v.w;
        }
        #pragma unroll
        for (int u = 0; u < 4; ++u) {
            int d = dq * 4 + u;
            float w0 = WT[(size_t)d * D_MODEL + t];
            float w1 = WT[(size_t)d * D_MODEL + 256 + t];
            #pragma unroll
            for (int r = 0; r < 8; ++r) {
                acc[r][0] = fmaf(a[r][u], w0, acc[r][0]);
                acc[r][1] = fmaf(a[r][u], w1, acc[r][1]);
            }
        }
    }

    const float b0 = bias[t], b1 = bias[256 + t];
    #pragma unroll
    for (int r = 0; r < 8; ++r) {
        out[(size_t)(n0 + r) * D_MODEL + t] = acc[r][0] + b0;
        out[(size_t)(n0 + r) * D_MODEL + 256 + t] = acc[r][1] + b1;
    }
}

extern "C" void kernel_launch(void* const* d_in, const int* in_sizes, int n_in,
                              void* d_out, int out_size, void* d_ws, size_t ws_size,
                              hipStream_t stream)
{
    const float* q      = (const float*)d_in[0];
    const float* k      = (const float*)d_in[1];
    const float* v      = (const float*)d_in[2];
    const float* coords = (const float*)d_in[3];
    const unsigned char* mask = (const unsigned char*)d_in[4];
    const float* q_proj = (const float*)d_in[5];
    const float* k_proj = (const float*)d_in[6];
    const float* v_proj = (const float*)d_in[7];
    const float* q_ln_w = (const float*)d_in[8];
    const float* q_ln_b = (const float*)d_in[9];
    const float* k_ln_w = (const float*)d_in[10];
    const float* k_ln_b = (const float*)d_in[11];
    const float* v_ln_w = (const float*)d_in[12];
    const float* v_ln_b = (const float*)d_in[13];
    const float* out_w  = (const float*)d_in[14];
    const float* out_b  = (const float*)d_in[15];
    float* out = (float*)d_out;

    // workspace layout (11 MB total)
    short* Qbf  = (short*)d_ws;                              // H*N*DK bf16
    short* Kbf  = Qbf + (size_t)NHEAD * N_TOK * DK;
    short* Vtbf = Kbf + (size_t)NHEAD * N_TOK * DK;          // [h][dk][n]
    float* ATT  = (float*)(Vtbf + (size_t)NHEAD * N_TOK * DK);
    float* WT   = ATT + (size_t)N_TOK * D_MODEL;

    proj_ln_kernel<0><<<dim3(N_TOK / 16, NHEAD), dim3(256), 0, stream>>>(q, q_proj, q_ln_w, q_ln_b, Qbf);
    proj_ln_kernel<0><<<dim3(N_TOK / 16, NHEAD), dim3(256), 0, stream>>>(k, k_proj, k_ln_w, k_ln_b, Kbf);
    proj_ln_kernel<1><<<dim3(N_TOK / 16, NHEAD), dim3(256), 0, stream>>>(v, v_proj, v_ln_w, v_ln_b, Vtbf);
    transpose_kernel<<<dim3(8, 8), dim3(256), 0, stream>>>(out_w, WT);
    attn_kernel<<<dim3(N_TOK / 32, NHEAD), dim3(128), 0, stream>>>(Qbf, Kbf, Vtbf, coords, mask, ATT);
    out_proj_kernel<<<dim3(N_TOK / 8), dim3(256), 0, stream>>>(ATT, WT, out_b, out);
}

// Round 4
// 88.272 us; speedup vs baseline: 5.6093x; 2.7133x over previous
//
#include <hip/hip_runtime.h>
#include <math.h>

#define N_TOK 2048
#define D_MODEL 512
#define NHEAD 8
#define DK 64

typedef __attribute__((ext_vector_type(8))) short short8;
typedef __attribute__((ext_vector_type(4))) short short4v;
typedef __attribute__((ext_vector_type(4))) float f32x4;

__device__ __forceinline__ short f2bf(float x) {
    unsigned u = __float_as_uint(x);
    u = (u + 0x7fffu + ((u >> 16) & 1u)) >> 16;   // round-to-nearest-even
    return (short)u;
}

// ---------------- Prep A: x (q,k,v) f32 -> bf16 ----------------
__global__ __launch_bounds__(256) void convert_x_kernel(
    const float* __restrict__ q, const float* __restrict__ k,
    const float* __restrict__ v, short* __restrict__ Xbf)
{
    int i = blockIdx.x * 256 + threadIdx.x;   // 8-elem chunk id
    int t = i >> 17;                          // 131072 chunks per tensor
    int rem = i & 131071;
    const float4* src = (const float4*)(t == 0 ? q : (t == 1 ? k : v));
    float4 a = src[rem * 2], b = src[rem * 2 + 1];
    short8 o;
    o[0] = f2bf(a.x); o[1] = f2bf(a.y); o[2] = f2bf(a.z); o[3] = f2bf(a.w);
    o[4] = f2bf(b.x); o[5] = f2bf(b.y); o[6] = f2bf(b.z); o[7] = f2bf(b.w);
    *(short8*)(Xbf + (size_t)i * 8) = o;
}

// ---------------- Prep B: weights -> bf16 (proj transposed) ----------------
// z<3: Wt[z][h*64+c][d] = proj_z[h][d][c] (bf16).  z==3: Wo = bf16(out_w).
__global__ __launch_bounds__(256) void prep_w_kernel(
    const float* __restrict__ qp, const float* __restrict__ kp,
    const float* __restrict__ vp, const float* __restrict__ ow,
    short* __restrict__ Wt, short* __restrict__ Wo)
{
    const int z = blockIdx.z, t = threadIdx.x;
    if (z == 3) {
        int m0 = blockIdx.x * 64, j0 = blockIdx.y * 64;
        for (int i = t; i < 4096; i += 256) {
            int r = i >> 6, c = i & 63;
            size_t idx = (size_t)(m0 + r) * 512 + j0 + c;
            Wo[idx] = f2bf(ow[idx]);
        }
        return;
    }
    const float* src = z == 0 ? qp : (z == 1 ? kp : vp);
    __shared__ float tile[64][65];
    const int h = blockIdx.x;          // head = aligned 64-wide col tile
    const int d0 = blockIdx.y * 64;
    for (int i = t; i < 4096; i += 256) {
        int r = i >> 6, c = i & 63;    // r: d-local, c: c-local
        tile[r][c] = src[((size_t)h * 512 + d0 + r) * 64 + c];
    }
    __syncthreads();
    short* W = Wt + (size_t)z * 512 * 512;
    for (int i = t; i < 4096; i += 256) {
        int cr = i >> 6, dc_ = i & 63;
        W[(size_t)(h * 64 + cr) * 512 + d0 + dc_] = f2bf(tile[dc_][cr]);
    }
}

// ---------------- Stage 1: projection + LayerNorm via bf16 MFMA ------------
// grid (N/64, H, 3), block 256 = 4 waves. Block: 64n x 64dk for one head.
// z selects tensor; z==2 (V) writes transposed [h][dk][n].
__global__ __launch_bounds__(256) void proj_ln_mfma_kernel(
    const short* __restrict__ Xbf, const short* __restrict__ Wt,
    const float* __restrict__ qlw, const float* __restrict__ qlb,
    const float* __restrict__ klw, const float* __restrict__ klb,
    const float* __restrict__ vlw, const float* __restrict__ vlb,
    short* __restrict__ Qbf, short* __restrict__ Kbf, short* __restrict__ Vtbf)
{
    __shared__ short Xs[64 * 64];
    __shared__ short Ws[64 * 64];
    const int z = blockIdx.z, h = blockIdx.y;
    const int n0 = blockIdx.x * 64;
    const int tid = threadIdx.x, w = tid >> 6, l = tid & 63;
    const int l15 = l & 15, lg = l >> 4;

    const short* X = Xbf + (size_t)z * N_TOK * D_MODEL;
    const short* Wz = Wt + ((size_t)z * 512 + h * 64) * 512;

    const f32x4 zero4 = {0.f, 0.f, 0.f, 0.f};
    f32x4 acc[4];
    #pragma unroll
    for (int dc = 0; dc < 4; ++dc) acc[dc] = zero4;

    for (int kb = 0; kb < 8; ++kb) {
        const int d0 = kb * 64;
        __syncthreads();
        #pragma unroll
        for (int i = 0; i < 2; ++i) {
            int c = tid + i * 256;
            int r = c >> 3, g = c & 7;
            short8 xv = *(const short8*)(X + (size_t)(n0 + r) * 512 + d0 + g * 8);
            *(short8*)(Xs + r * 64 + ((g * 8) ^ ((r & 7) << 3))) = xv;
            short8 wv = *(const short8*)(Wz + (size_t)r * 512 + d0 + g * 8);
            *(short8*)(Ws + r * 64 + ((g * 8) ^ ((r & 7) << 3))) = wv;
        }
        __syncthreads();
        const int arow = w * 16 + l15;
        short8 a0 = *(const short8*)(Xs + arow * 64 + ((lg * 8) ^ ((arow & 7) << 3)));
        short8 a1 = *(const short8*)(Xs + arow * 64 + ((32 + lg * 8) ^ ((arow & 7) << 3)));
        #pragma unroll
        for (int dc = 0; dc < 4; ++dc) {
            const int brow = dc * 16 + l15;
            short8 b0 = *(const short8*)(Ws + brow * 64 + ((lg * 8) ^ ((brow & 7) << 3)));
            acc[dc] = __builtin_amdgcn_mfma_f32_16x16x32_bf16(a0, b0, acc[dc], 0, 0, 0);
            short8 b1 = *(const short8*)(Ws + brow * 64 + ((32 + lg * 8) ^ ((brow & 7) << 3)));
            acc[dc] = __builtin_amdgcn_mfma_f32_16x16x32_bf16(a1, b1, acc[dc], 0, 0, 0);
        }
    }

    // LayerNorm epilogue: row = n (lg*4+reg), 64 cols spread over l15 x dc.
    const float* lw = z == 0 ? qlw : (z == 1 ? klw : vlw);
    const float* lbp = z == 0 ? qlb : (z == 1 ? klb : vlb);
    float wv_[4], bv_[4];
    #pragma unroll
    for (int dc = 0; dc < 4; ++dc) {
        wv_[dc] = lw[dc * 16 + l15];
        bv_[dc] = lbp[dc * 16 + l15];
    }
    float mu[4], rs[4];
    #pragma unroll
    for (int reg = 0; reg < 4; ++reg) {
        float s = acc[0][reg] + acc[1][reg] + acc[2][reg] + acc[3][reg];
        #pragma unroll
        for (int off = 1; off < 16; off <<= 1) s += __shfl_xor(s, off);
        float m = s * (1.0f / 64.0f);
        float ss = 0.f;
        #pragma unroll
        for (int dc = 0; dc < 4; ++dc) { float d = acc[dc][reg] - m; ss += d * d; }
        #pragma unroll
        for (int off = 1; off < 16; off <<= 1) ss += __shfl_xor(ss, off);
        mu[reg] = m;
        rs[reg] = rsqrtf(ss * (1.0f / 64.0f) + 1e-5f);
    }
    if (z < 2) {
        short* out = (z == 0) ? Qbf : Kbf;
        #pragma unroll
        for (int dc = 0; dc < 4; ++dc)
            #pragma unroll
            for (int reg = 0; reg < 4; ++reg) {
                int n = n0 + w * 16 + lg * 4 + reg;
                float val = (acc[dc][reg] - mu[reg]) * rs[reg] * wv_[dc] + bv_[dc];
                out[((size_t)h * N_TOK + n) * DK + dc * 16 + l15] = f2bf(val);
            }
    } else {
        #pragma unroll
        for (int dc = 0; dc < 4; ++dc) {
            short4v p;
            #pragma unroll
            for (int reg = 0; reg < 4; ++reg)
                p[reg] = f2bf((acc[dc][reg] - mu[reg]) * rs[reg] * wv_[dc] + bv_[dc]);
            *(short4v*)(Vtbf + ((size_t)h * DK + dc * 16 + l15) * N_TOK +
                        n0 + w * 16 + lg * 4) = p;
        }
    }
}

// ---------------- Stage 2: split-K flash attention (bf16 MFMA) -------------
// grid (N/16, H), block 256 = 4 waves. All waves share the same 16 q-rows;
// wave w covers keys [w*512, w*512+512) with PRIVATE LDS staging (no block
// barriers in the main loop). Final merge of (m,l,O) across waves via LDS.
#define WSZ 9216   // per-wave LDS bytes: K 4096 + Vt 4096 + P 1024
__global__ __launch_bounds__(256) void attn_kernel(
    const short* __restrict__ Qbf, const short* __restrict__ Kbf,
    const short* __restrict__ Vtbf, const float* __restrict__ coords,
    const unsigned char* __restrict__ mask, short* __restrict__ att)
{
    __shared__ __align__(16) char smem[4 * WSZ];

    const int tid = threadIdx.x;
    const int w = tid >> 6, l = tid & 63;
    const int l15 = l & 15, lg = l >> 4;
    const int h = blockIdx.y;
    const int n0 = blockIdx.x * 16;

    char* base = smem + w * WSZ;
    short* Kw  = (short*)base;            // [32][64] swizzled (r&7)<<3
    short* Vtw = (short*)(base + 4096);   // [64][32] swizzled ((r>>1)&3)<<3
    short* Pw  = (short*)(base + 8192);   // [16][32] swizzled ((r>>1)&3)<<3

    // Q fragments (same 16 rows for all waves)
    const short* Qrow = Qbf + ((size_t)h * N_TOK + n0 + l15) * DK + lg * 8;
    const short8 qf0 = *(const short8*)(Qrow);
    const short8 qf1 = *(const short8*)(Qrow + 32);

    float tt = (float)h * (1.0f / 7.0f);
    float sp = 1.0f + 5.0f * (powf(20.0f, tt) - 1.0f) * (1.0f / 19.0f);
    float nis2 = -1.0f / (2.0f * sp * sp);

    float qx[4], qy[4], qz[4];
    #pragma unroll
    for (int reg = 0; reg < 4; ++reg) {
        int n = n0 + lg * 4 + reg;
        qx[reg] = coords[n * 3 + 0];
        qy[reg] = coords[n * 3 + 1];
        qz[reg] = coords[n * 3 + 2];
    }

    const f32x4 zero4 = {0.f, 0.f, 0.f, 0.f};
    float m_[4], l_[4];
    f32x4 oacc[4];
    #pragma unroll
    for (int i = 0; i < 4; ++i) { m_[i] = -INFINITY; l_[i] = 0.f; oacc[i] = zero4; }

    const short* Kh = Kbf + (size_t)h * N_TOK * DK;
    const short* Vth = Vtbf + (size_t)h * DK * N_TOK;

    for (int t = 0; t < 16; ++t) {
        const int kbase = w * 512 + t * 32;
        // ---- private staging (wave-local, program-order safe) ----
        short8 kc[4], vc[4];
        #pragma unroll
        for (int i = 0; i < 4; ++i) {
            int c = i * 64 + l;
            int r = c >> 3, g = c & 7;
            kc[i] = *(const short8*)(Kh + (size_t)(kbase + r) * DK + g * 8);
        }
        #pragma unroll
        for (int i = 0; i < 4; ++i) {
            int c = i * 64 + l;
            int r = c >> 3, g = c & 7;
            *(short8*)(Kw + r * 64 + ((g * 8) ^ ((r & 7) << 3))) = kc[i];
        }
        #pragma unroll
        for (int i = 0; i < 4; ++i) {
            int c = i * 64 + l;
            int r = c >> 2, g = c & 3;
            vc[i] = *(const short8*)(Vth + (size_t)r * N_TOK + kbase + g * 8);
        }
        #pragma unroll
        for (int i = 0; i < 4; ++i) {
            int c = i * 64 + l;
            int r = c >> 2, g = c & 3;
            *(short8*)(Vtw + r * 32 + ((g * 8) ^ (((r >> 1) & 3) << 3))) = vc[i];
        }

        // ---- QK^T: S[16q x 32k] ----
        f32x4 sacc[2];
        sacc[0] = zero4; sacc[1] = zero4;
        #pragma unroll
        for (int nc = 0; nc < 2; ++nc) {
            int krow = nc * 16 + l15;
            int eb = krow * 64, sw = (krow & 7) << 3;
            short8 kb0 = *(const short8*)(Kw + eb + ((lg * 8) ^ sw));
            sacc[nc] = __builtin_amdgcn_mfma_f32_16x16x32_bf16(qf0, kb0, sacc[nc], 0, 0, 0);
            short8 kb1 = *(const short8*)(Kw + eb + ((32 + lg * 8) ^ sw));
            sacc[nc] = __builtin_amdgcn_mfma_f32_16x16x32_bf16(qf1, kb1, sacc[nc], 0, 0, 0);
        }

        float kx[2], ky[2], kz[2], km[2];
        #pragma unroll
        for (int nc = 0; nc < 2; ++nc) {
            int j = kbase + nc * 16 + l15;
            kx[nc] = coords[j * 3 + 0];
            ky[nc] = coords[j * 3 + 1];
            kz[nc] = coords[j * 3 + 2];
            km[nc] = (float)mask[j];
        }

        // ---- rbf + mask + online softmax ----
        float corr[4];
        #pragma unroll
        for (int reg = 0; reg < 4; ++reg) {
            float sv[2];
            #pragma unroll
            for (int nc = 0; nc < 2; ++nc) {
                float dx = qx[reg] - kx[nc];
                float dy = qy[reg] - ky[nc];
                float dz = qz[reg] - kz[nc];
                float d2 = dx * dx + dy * dy + dz * dz;
                float rb = __expf(d2 * nis2);
                rb = fminf(fmaxf(rb, 0.1f), 0.9f);
                float sc = sacc[nc][reg] * 0.125f * rb;
                sv[nc] = (km[nc] != 0.0f) ? -1e9f : sc;
            }
            float mx = fmaxf(sv[0], sv[1]);
            #pragma unroll
            for (int off = 1; off < 16; off <<= 1) mx = fmaxf(mx, __shfl_xor(mx, off));
            float mn = fmaxf(m_[reg], mx);
            float c0 = __expf(m_[reg] - mn);
            m_[reg] = mn;
            float p[2], ps = 0.f;
            #pragma unroll
            for (int nc = 0; nc < 2; ++nc) { p[nc] = __expf(sv[nc] - mn); ps += p[nc]; }
            #pragma unroll
            for (int off = 1; off < 16; off <<= 1) ps += __shfl_xor(ps, off);
            l_[reg] = l_[reg] * c0 + ps;
            corr[reg] = c0;
            int prow = lg * 4 + reg;
            int psw = ((prow >> 1) & 3) << 3;
            #pragma unroll
            for (int nc = 0; nc < 2; ++nc)
                Pw[prow * 32 + ((nc * 16 + l15) ^ psw)] = f2bf(p[nc]);
        }
        #pragma unroll
        for (int dc = 0; dc < 4; ++dc)
            #pragma unroll
            for (int reg = 0; reg < 4; ++reg) oacc[dc][reg] *= corr[reg];

        // ---- PV: O[16 x 64] += P[16 x 32] * V[32 x 64] ----
        short8 pa = *(const short8*)(Pw + l15 * 32 + ((lg * 8) ^ (((l15 >> 1) & 3) << 3)));
        #pragma unroll
        for (int dc = 0; dc < 4; ++dc) {
            int dr = dc * 16 + l15;
            short8 vb = *(const short8*)(Vtw + dr * 32 + ((lg * 8) ^ (((dr >> 1) & 3) << 3)));
            oacc[dc] = __builtin_amdgcn_mfma_f32_16x16x32_bf16(pa, vb, oacc[dc], 0, 0, 0);
        }
    }

    // ---- cross-wave merge (reuse own staging LDS region) ----
    float* mb = (float*)base;          // [16]
    float* lb = mb + 16;               // [16]
    float* Ob = mb + 32;               // [16][64]
    if (w > 0) {
        if (l15 == 0) {
            #pragma unroll
            for (int reg = 0; reg < 4; ++reg) {
                mb[lg * 4 + reg] = m_[reg];
                lb[lg * 4 + reg] = l_[reg];
            }
        }
        #pragma unroll
        for (int dc = 0; dc < 4; ++dc)
            #pragma unroll
            for (int reg = 0; reg < 4; ++reg)
                Ob[(lg * 4 + reg) * 64 + dc * 16 + l15] = oacc[dc][reg];
    }
    __syncthreads();
    if (w == 0) {
        #pragma unroll
        for (int reg = 0; reg < 4; ++reg) {
            const int row = lg * 4 + reg;
            float M = m_[reg];
            #pragma unroll
            for (int u = 1; u < 4; ++u)
                M = fmaxf(M, ((float*)(smem + u * WSZ))[row]);
            float f0 = __expf(m_[reg] - M);
            float lt = l_[reg] * f0;
            float Ot[4];
            #pragma unroll
            for (int dc = 0; dc < 4; ++dc) Ot[dc] = oacc[dc][reg] * f0;
            #pragma unroll
            for (int u = 1; u < 4; ++u) {
                float* ub = (float*)(smem + u * WSZ);
                float fu = __expf(ub[row] - M);
                lt += ub[16 + row] * fu;
                float* uO = ub + 32 + row * 64;
                #pragma unroll
                for (int dc = 0; dc < 4; ++dc)
                    Ot[dc] += uO[dc * 16 + l15] * fu;
            }
            float rl = 1.0f / lt;
            int n = n0 + row;
            #pragma unroll
            for (int dc = 0; dc < 4; ++dc)
                att[(size_t)n * D_MODEL + (dc * 16 + l15) * NHEAD + h] =
                    f2bf(Ot[dc] * rl);
        }
    }
}

// ---------------- Stage 3: output projection via bf16 MFMA ----------------
// grid (N/64, 8), block 256 = 4 waves; 64n x 64m tile, K=512.
// B operand = out_w rows (already [m][j], contiguous j).
__global__ __launch_bounds__(256) void out_proj_kernel(
    const short* __restrict__ ATT, const short* __restrict__ Wo,
    const float* __restrict__ bias, float* __restrict__ out)
{
    __shared__ short As[64 * 64];
    __shared__ short Bs[64 * 64];
    const int n0 = blockIdx.x * 64, m0 = blockIdx.y * 64;
    const int tid = threadIdx.x, w = tid >> 6, l = tid & 63;
    const int l15 = l & 15, lg = l >> 4;

    const f32x4 zero4 = {0.f, 0.f, 0.f, 0.f};
    f32x4 acc[4];
    #pragma unroll
    for (int dc = 0; dc < 4; ++dc) acc[dc] = zero4;

    for (int kb = 0; kb < 8; ++kb) {
        const int j0 = kb * 64;
        __syncthreads();
        #pragma unroll
        for (int i = 0; i < 2; ++i) {
            int c = tid + i * 256;
            int r = c >> 3, g = c & 7;
            short8 av = *(const short8*)(ATT + (size_t)(n0 + r) * 512 + j0 + g * 8);
            *(short8*)(As + r * 64 + ((g * 8) ^ ((r & 7) << 3))) = av;
            short8 bv = *(const short8*)(Wo + (size_t)(m0 + r) * 512 + j0 + g * 8);
            *(short8*)(Bs + r * 64 + ((g * 8) ^ ((r & 7) << 3))) = bv;
        }
        __syncthreads();
        const int arow = w * 16 + l15;
        short8 a0 = *(const short8*)(As + arow * 64 + ((lg * 8) ^ ((arow & 7) << 3)));
        short8 a1 = *(const short8*)(As + arow * 64 + ((32 + lg * 8) ^ ((arow & 7) << 3)));
        #pragma unroll
        for (int dc = 0; dc < 4; ++dc) {
            const int brow = dc * 16 + l15;
            short8 b0 = *(const short8*)(Bs + brow * 64 + ((lg * 8) ^ ((brow & 7) << 3)));
            acc[dc] = __builtin_amdgcn_mfma_f32_16x16x32_bf16(a0, b0, acc[dc], 0, 0, 0);
            short8 b1 = *(const short8*)(Bs + brow * 64 + ((32 + lg * 8) ^ ((brow & 7) << 3)));
            acc[dc] = __builtin_amdgcn_mfma_f32_16x16x32_bf16(a1, b1, acc[dc], 0, 0, 0);
        }
    }

    #pragma unroll
    for (int dc = 0; dc < 4; ++dc) {
        float bm = bias[m0 + dc * 16 + l15];
        #pragma unroll
        for (int reg = 0; reg < 4; ++reg) {
            int n = n0 + w * 16 + lg * 4 + reg;
            out[(size_t)n * D_MODEL + m0 + dc * 16 + l15] = acc[dc][reg] + bm;
        }
    }
}

extern "C" void kernel_launch(void* const* d_in, const int* in_sizes, int n_in,
                              void* d_out, int out_size, void* d_ws, size_t ws_size,
                              hipStream_t stream)
{
    const float* q      = (const float*)d_in[0];
    const float* k      = (const float*)d_in[1];
    const float* v      = (const float*)d_in[2];
    const float* coords = (const float*)d_in[3];
    const unsigned char* mask = (const unsigned char*)d_in[4];
    const float* q_proj = (const float*)d_in[5];
    const float* k_proj = (const float*)d_in[6];
    const float* v_proj = (const float*)d_in[7];
    const float* q_ln_w = (const float*)d_in[8];
    const float* q_ln_b = (const float*)d_in[9];
    const float* k_ln_w = (const float*)d_in[10];
    const float* k_ln_b = (const float*)d_in[11];
    const float* v_ln_w = (const float*)d_in[12];
    const float* v_ln_b = (const float*)d_in[13];
    const float* out_w  = (const float*)d_in[14];
    const float* out_b  = (const float*)d_in[15];
    float* out = (float*)d_out;

    // workspace layout (bf16 shorts, 16 MB total)
    short* Xbf  = (short*)d_ws;            // 3*2048*512
    short* Wt   = Xbf + 3145728;           // 3*512*512
    short* Wo   = Wt + 786432;             // 512*512
    short* Qbf  = Wo + 262144;             // 8*2048*64
    short* Kbf  = Qbf + 1048576;
    short* Vtbf = Kbf + 1048576;           // [h][dk][n]
    short* ATT  = Vtbf + 1048576;          // [n][dk*8+h]

    convert_x_kernel<<<dim3(1536), dim3(256), 0, stream>>>(q, k, v, Xbf);
    prep_w_kernel<<<dim3(8, 8, 4), dim3(256), 0, stream>>>(q_proj, k_proj, v_proj, out_w, Wt, Wo);
    proj_ln_mfma_kernel<<<dim3(32, 8, 3), dim3(256), 0, stream>>>(
        Xbf, Wt, q_ln_w, q_ln_b, k_ln_w, k_ln_b, v_ln_w, v_ln_b, Qbf, Kbf, Vtbf);
    attn_kernel<<<dim3(128, 8), dim3(256), 0, stream>>>(Qbf, Kbf, Vtbf, coords, mask, ATT);
    out_proj_kernel<<<dim3(32, 8), dim3(256), 0, stream>>>(ATT, Wo, out_b, out);
}